// Round 6
// baseline (2418.803 us; speedup 1.0000x reference)
//
#include <hip/hip_runtime.h>
#include <hip/hip_bf16.h>

typedef short    bf16x8 __attribute__((ext_vector_type(8)));
typedef float    f32x4  __attribute__((ext_vector_type(4)));
typedef unsigned u32x4  __attribute__((ext_vector_type(4)));

#define RNN_H 128
#define RNN_T 2048
#define RNN_B 8192
#define RNN_C 10
#define BLK_N 32   // two 16-col tiles per block (A and B), pipelined in-wave

template <typename D, typename S>
__device__ __forceinline__ D bitcast(const S& s) {
  static_assert(sizeof(D) == sizeof(S), "size mismatch");
  D d; __builtin_memcpy(&d, &s, sizeof(D)); return d;
}

__device__ __forceinline__ unsigned pk_bf16(float a0, float a1) {
  __hip_bfloat162 b2 = __float22bfloat162_rn(make_float2(a0, a1));
  unsigned u; __builtin_memcpy(&u, &b2, 4);
  return u;  // a0 in low 16, a1 in high 16
}

// setup-time RNE split for W: a ~= hi + lo, residual ~2^-17 |a|
__device__ __forceinline__ void split2(float a0, float a1, unsigned &hp, unsigned &lp) {
  hp = pk_bf16(a0, a1);
  float h0 = __uint_as_float(hp << 16);
  float h1 = __uint_as_float(hp & 0xffff0000u);
  lp = pk_bf16(a0 - h0, a1 - h1);
}

__device__ __forceinline__ float fast_tanh(float a) {
  // tanh(a) = 1 - 2/(exp(2a)+1)
  float e = __builtin_amdgcn_exp2f(a * 2.885390081777927f);
  return 1.0f - 2.0f * __builtin_amdgcn_rcpf(e + 1.0f);
}

__device__ __forceinline__ f32x4 mfma16(bf16x8 a, bf16x8 b, f32x4 c) {
  return __builtin_amdgcn_mfma_f32_16x16x32_bf16(a, b, c, 0, 0, 0);
}

// k-bijection for 16x16x32 frags (same map for A-load and B-store, so the true
// HW k-layout cancels): slot (g = lane>>4, j) -> k = 4*g + (j&3) + 16*(j>>2).
// Each thread's 8 C/D values (row = 16*mt + 4*g + r) form one lane-local
// bf16x8 B-slot -> single ds_write_b128 per hi/lo half.

// LDS-only barrier: drain ds ops, never vmcnt (x prefetch stays in flight).
#define BAR() asm volatile("s_waitcnt lgkmcnt(0)\n\ts_barrier" ::: "memory")

#define SGB(mask, n) __builtin_amdgcn_sched_group_barrier((mask), (n), 0)

__global__ __launch_bounds__(256, 1)
void rnn_fused(const float* __restrict__ x, const float* __restrict__ w_hx,
               const float* __restrict__ w_hh, const float* __restrict__ b_h,
               const float* __restrict__ w_ph, const float* __restrict__ b_p,
               float* __restrict__ out)
{
  // Single-buffered h per tile, B-frag order: [tile][hi/lo][kt(4)][lane(64)].
  // 16 KiB. Write->read pairs are barrier-separated by the 2-phase schedule.
  __shared__ bf16x8 hbuf[2][2][4][64];

  const int tid  = threadIdx.x;
  const int lane = tid & 63;
  const int wv   = tid >> 6;   // wave owns rows 32*wv .. 32*wv+31
  const int g    = lane >> 4;
  const int l15  = lane & 15;
  const int n0   = blockIdx.x * BLK_N;

  { // zero initial h for both tiles
    bf16x8 z = {0,0,0,0,0,0,0,0};
    bf16x8* p = &hbuf[0][0][0][0];
    for (int i = tid; i < 2*2*4*64; i += 256) p[i] = z;
  }

  // ---- W_hh hi/lo A-fragments, register-resident (64 VGPRs), shared by A/B ----
  bf16x8 Ahi[2][4], Alo[2][4];
  #pragma unroll
  for (int mt = 0; mt < 2; ++mt) {
    const float* wrow = w_hh + (size_t)(wv*32 + mt*16 + l15)*RNN_H + 4*g;
    #pragma unroll
    for (int kt = 0; kt < 4; ++kt) {
      f32x4 w0 = *(const f32x4*)(wrow + kt*32);        // j=0..3  (k off 0..3)
      f32x4 w1 = *(const f32x4*)(wrow + kt*32 + 16);   // j=4..7  (k off 16..19)
      unsigned h0,h1,h2,h3,l0,l1,l2,l3;
      split2(w0[0], w0[1], h0, l0);
      split2(w0[2], w0[3], h1, l1);
      split2(w1[0], w1[1], h2, l2);
      split2(w1[2], w1[3], h3, l3);
      u32x4 th = {h0,h1,h2,h3}, tl = {l0,l1,l2,l3};
      Ahi[mt][kt] = bitcast<bf16x8>(th);
      Alo[mt][kt] = bitcast<bf16x8>(tl);
    }
  }

  // bias / w_hx per C/D reg: m = wv*32 + mt*16 + 4*g + r
  f32x4 bh[2], wx[2];
  #pragma unroll
  for (int mt = 0; mt < 2; ++mt)
    #pragma unroll
    for (int r = 0; r < 4; ++r) {
      const int m = wv*32 + mt*16 + 4*g + r;
      bh[mt][r] = b_h[m];
      wx[mt][r] = w_hx[m];
    }

  // x streams for this lane's two batch columns (tile A, tile B)
  const float* pxA = x + (size_t)(n0 + l15) * RNN_T;
  const float* pxB = x + (size_t)(n0 + 16 + l15) * RNN_T;
  f32x4 xcA = *(const f32x4*)pxA;
  f32x4 xcB = *(const f32x4*)pxB;

  const f32x4 ZV = {0.0f, 0.0f, 0.0f, 0.0f};

  // accumulators; B primed to zero so first epi_B writes h_B(0) = tanh(0) = 0
  f32x4 cA0[2], cA1[2], cA2[2], cB0[2], cB1[2], cB2[2];
  #pragma unroll
  for (int mt = 0; mt < 2; ++mt) {
    cB0[mt] = ZV; cB1[mt] = ZV; cB2[mt] = ZV;
    cA0[mt] = ZV; cA1[mt] = ZV; cA2[mt] = ZV;
  }

  __syncthreads();

  // One phase: ds_read MFMA-tile h; epilogue of the OTHER tile (pure VALU,
  // independent) fills the LDS latency and the MFMA issue gaps; MFMAs; write
  // the other tile's new h; sched_group_barrier template enforces the
  // 1-MFMA : 4-VALU interleave (in-order issue would otherwise stall the
  // whole wave at each back-to-back MFMA issue).
  auto phase = [&](int RT, int WT, float xv,
                   f32x4 (&cM0)[2], f32x4 (&cM1)[2], f32x4 (&cM2)[2],
                   f32x4 (&cE0)[2], f32x4 (&cE1)[2], f32x4 (&cE2)[2]) {
    // (a) LDS loads for the MFMA tile
    bf16x8 bhv[4], blv[4];
    #pragma unroll
    for (int kt = 0; kt < 4; ++kt) {
      bhv[kt] = hbuf[RT][0][kt][lane];
      blv[kt] = hbuf[RT][1][kt][lane];
    }
    // (b) epilogue of the other tile (VALU only)
    unsigned hw[4], lw[4];
    #pragma unroll
    for (int w = 0; w < 4; ++w) {
      const int emt = w >> 1, r0 = 2*(w & 1);
      const float v0 = (cE0[emt][r0]   + cE1[emt][r0])   + cE2[emt][r0];
      const float v1 = (cE0[emt][r0+1] + cE1[emt][r0+1]) + cE2[emt][r0+1];
      const float t0 = fast_tanh(v0);
      const float t1 = fast_tanh(v1);
      const unsigned u0 = __float_as_uint(t0), u1 = __float_as_uint(t1);
      const unsigned hp = (u1 & 0xffff0000u) | (u0 >> 16);  // trunc-bf16 pack
      hw[w] = hp;
      const float e0 = t0 - __uint_as_float(hp << 16);      // exact residual
      const float e1 = t1 - __uint_as_float(hp & 0xffff0000u);
      lw[w] = pk_bf16(e0, e1);
    }
    // (c) pre-activation init + 24 MFMAs (6 independent chains)
    #pragma unroll
    for (int mt = 0; mt < 2; ++mt)
      #pragma unroll
      for (int r = 0; r < 4; ++r)
        cM0[mt][r] = __builtin_fmaf(wx[mt][r], xv, bh[mt][r]);
    #pragma unroll
    for (int kt = 0; kt < 4; ++kt) {
      cM0[0] = mfma16(Ahi[0][kt], bhv[kt], cM0[0]);
      cM0[1] = mfma16(Ahi[1][kt], bhv[kt], cM0[1]);
      cM1[0] = mfma16(Alo[0][kt], bhv[kt], kt ? cM1[0] : ZV);
      cM1[1] = mfma16(Alo[1][kt], bhv[kt], kt ? cM1[1] : ZV);
      cM2[0] = mfma16(Ahi[0][kt], blv[kt], kt ? cM2[0] : ZV);
      cM2[1] = mfma16(Ahi[1][kt], blv[kt], kt ? cM2[1] : ZV);
    }
    // (d) write the other tile's new h
    u32x4 a = {hw[0],hw[1],hw[2],hw[3]}, b = {lw[0],lw[1],lw[2],lw[3]};
    hbuf[WT][0][wv][lane] = bitcast<bf16x8>(a);
    hbuf[WT][1][wv][lane] = bitcast<bf16x8>(b);
    // (e) schedule template for this region: reads first, epi head to cover
    // LDS latency, then 1 MFMA : 4 VALU, writes last.
    SGB(0x100, 8);            // 8 ds_read
    SGB(0x002, 24);           // epi-head VALU
    #pragma unroll
    for (int i = 0; i < 24; ++i) {
      SGB(0x008, 1);          // 1 MFMA
      SGB(0x002, 4);          // 4 VALU
    }
    SGB(0x200, 2);            // 2 ds_write
    BAR();
  };

  for (int t4 = 0; t4 < RNN_T/4; ++t4) {
    f32x4 xnA = xcA, xnB = xcB;
    if (t4 + 1 < RNN_T/4) {
      xnA = *(const f32x4*)(pxA + 4*t4 + 4);
      xnB = *(const f32x4*)(pxB + 4*t4 + 4);
    }
    #pragma unroll
    for (int q = 0; q < 4; ++q) {
      // P1: MFMA_A(t) reads hbuf[0]=h_A(t); epi_B(t-1) writes hbuf[1]=h_B(t)
      phase(0, 1, xcA[q], cA0, cA1, cA2, cB0, cB1, cB2);
      // P2: MFMA_B(t) reads hbuf[1]=h_B(t); epi_A(t) writes hbuf[0]=h_A(t+1)
      phase(1, 0, xcB[q], cB0, cB1, cB2, cA0, cA1, cA2);
    }
    xcA = xnA; xcB = xnB;
  }

  // drain: tile B's last epilogue -> h_B(T) into hbuf[1]
  {
    unsigned hw[4], lw[4];
    #pragma unroll
    for (int w = 0; w < 4; ++w) {
      const int emt = w >> 1, r0 = 2*(w & 1);
      const float v0 = (cB0[emt][r0]   + cB1[emt][r0])   + cB2[emt][r0];
      const float v1 = (cB0[emt][r0+1] + cB1[emt][r0+1]) + cB2[emt][r0+1];
      const float t0 = fast_tanh(v0);
      const float t1 = fast_tanh(v1);
      const unsigned u0 = __float_as_uint(t0), u1 = __float_as_uint(t1);
      const unsigned hp = (u1 & 0xffff0000u) | (u0 >> 16);
      hw[w] = hp;
      const float e0 = t0 - __uint_as_float(hp << 16);
      const float e1 = t1 - __uint_as_float(hp & 0xffff0000u);
      lw[w] = pk_bf16(e0, e1);
    }
    u32x4 a = {hw[0],hw[1],hw[2],hw[3]}, b = {lw[0],lw[1],lw[2],lw[3]};
    hbuf[1][0][wv][lane] = bitcast<bf16x8>(a);
    hbuf[1][1][wv][lane] = bitcast<bf16x8>(b);
  }
  __syncthreads();

  // ---- projection: out[b][c] = w_ph[c,:] . h_last[:,b] + b_p[c] ----
  // h_A(T) in hbuf[0], h_B(T) in hbuf[1].
  #pragma unroll
  for (int pass = 0; pass < 2; ++pass) {
    const int idx = tid + pass*256;
    const int c   = idx >> 5;
    const int n32 = idx & 31;
    if (c < RNN_C) {
      const int tile = n32 >> 4;
      const int n    = n32 & 15;
      float sum = b_p[c];
      for (int k = 0; k < RNN_H; ++k) {
        const int kt = k >> 5;
        const int l  = 16*((k & 15) >> 2) + n;
        const int j  = (k & 3) + 4*((k >> 4) & 1);
        const unsigned short* ph = (const unsigned short*)&hbuf[tile][0][kt][l];
        const unsigned short* pl = (const unsigned short*)&hbuf[tile][1][kt][l];
        const float hv = __uint_as_float(((unsigned)ph[j]) << 16)
                       + __uint_as_float(((unsigned)pl[j]) << 16);
        sum = __builtin_fmaf(w_ph[c*RNN_H + k], hv, sum);
      }
      out[(size_t)(n0 + n32)*RNN_C + c] = sum;
    }
  }
}

extern "C" void kernel_launch(void* const* d_in, const int* in_sizes, int n_in,
                              void* d_out, int out_size, void* d_ws, size_t ws_size,
                              hipStream_t stream) {
  (void)in_sizes; (void)n_in; (void)out_size; (void)d_ws; (void)ws_size;
  const float* x    = (const float*)d_in[0];
  const float* w_hx = (const float*)d_in[1];
  const float* w_hh = (const float*)d_in[2];
  const float* b_h  = (const float*)d_in[3];
  const float* w_ph = (const float*)d_in[4];
  const float* b_p  = (const float*)d_in[5];
  float* out = (float*)d_out;
  rnn_fused<<<dim3(RNN_B/BLK_N), dim3(256), 0, stream>>>(x, w_hx, w_hh, b_h, w_ph, b_p, out);
}

// Round 7
// 1819.769 us; speedup vs baseline: 1.3292x; 1.3292x over previous
//
#include <hip/hip_runtime.h>
#include <hip/hip_bf16.h>

typedef short    bf16x8 __attribute__((ext_vector_type(8)));
typedef float    f32x4  __attribute__((ext_vector_type(4)));
typedef unsigned u32x2  __attribute__((ext_vector_type(2)));
typedef unsigned u32x4  __attribute__((ext_vector_type(4)));

#define RNN_H 128
#define RNN_T 2048
#define RNN_B 8192
#define RNN_C 10
#define BLK_N 16

template <typename D, typename S>
__device__ __forceinline__ D bitcast(const S& s) {
  static_assert(sizeof(D) == sizeof(S), "size mismatch");
  D d; __builtin_memcpy(&d, &s, sizeof(D)); return d;
}

__device__ __forceinline__ unsigned pk_bf16(float a0, float a1) {
  __hip_bfloat162 b2 = __float22bfloat162_rn(make_float2(a0, a1));
  unsigned u; __builtin_memcpy(&u, &b2, 4);
  return u;  // a0 in low 16, a1 in high 16
}

// setup-time RNE split for W: a ~= hi + lo, residual ~2^-17 |a|
__device__ __forceinline__ void split2(float a0, float a1, unsigned &hp, unsigned &lp) {
  hp = pk_bf16(a0, a1);
  float h0 = __uint_as_float(hp << 16);
  float h1 = __uint_as_float(hp & 0xffff0000u);
  lp = pk_bf16(a0 - h0, a1 - h1);
}

__device__ __forceinline__ float fast_tanh(float a) {
  // tanh(a) = 1 - 2/(exp(2a)+1)
  float e = __builtin_amdgcn_exp2f(a * 2.885390081777927f);
  return 1.0f - 2.0f * __builtin_amdgcn_rcpf(e + 1.0f);
}

__device__ __forceinline__ f32x4 mfma16(bf16x8 a, bf16x8 b, f32x4 c) {
  return __builtin_amdgcn_mfma_f32_16x16x32_bf16(a, b, c, 0, 0, 0);
}

// k-bijection for 16x16x32 frags (same map for A-load and B-store, so the true
// HW k-layout cancels): slot (g = lane>>4, j) -> k = 4*g + (j&3) + 16*(j>>2).
// A wave owning rows [16*wv, 16*wv+16) produces, per lane, exactly the j-half
// (j = 4*(wv&1) + r) of B-slot kt = wv>>1 -> lane-local register recycle; only
// the partner's j-half (b64) + the other 3 kt tiles (b128) come from LDS.

// LDS-only barrier: drain ds ops, never vmcnt (x prefetch stays in flight).
#define BAR() asm volatile("s_waitcnt lgkmcnt(0)\n\ts_barrier" ::: "memory")

__global__ __launch_bounds__(512, 4)
void rnn_fused(const float* __restrict__ x, const float* __restrict__ w_hx,
               const float* __restrict__ w_hh, const float* __restrict__ b_h,
               const float* __restrict__ w_ph, const float* __restrict__ b_p,
               float* __restrict__ out)
{
  // h double-buffered, B-frag order: [buf][hi/lo][kt(4)][lane(64)]. 16 KiB.
  __shared__ bf16x8 hbuf[2][2][4][64];

  const int tid  = threadIdx.x;
  const int lane = tid & 63;
  const int wv   = tid >> 6;     // 0..7: rows [16*wv, 16*wv+16)
  const int g    = lane >> 4;
  const int l15  = lane & 15;
  const int n0   = blockIdx.x * BLK_N;
  const int ownkt   = wv >> 1;   // this wave's B-slot kt tile
  const int ownhalf = wv & 1;    // j-half within that slot (0: j0-3, 1: j4-7)

  { // zero h(0) = buffer 0 (512 slots, 512 threads)
    bf16x8 z = {0,0,0,0,0,0,0,0};
    (&hbuf[0][0][0][0])[tid] = z;
  }

  // ---- W_hh hi/lo A-fragments for this wave's 16 rows (32 VGPRs) ----
  bf16x8 Ahi[4], Alo[4];
  {
    const float* wrow = w_hh + (size_t)(wv*16 + l15)*RNN_H + 4*g;
    #pragma unroll
    for (int kt = 0; kt < 4; ++kt) {
      f32x4 w0 = *(const f32x4*)(wrow + kt*32);        // j=0..3 (k off 0..3)
      f32x4 w1 = *(const f32x4*)(wrow + kt*32 + 16);   // j=4..7 (k off 16..19)
      unsigned h0,h1,h2,h3,l0,l1,l2,l3;
      split2(w0[0], w0[1], h0, l0);
      split2(w0[2], w0[3], h1, l1);
      split2(w1[0], w1[1], h2, l2);
      split2(w1[2], w1[3], h3, l3);
      u32x4 th = {h0,h1,h2,h3}, tl = {l0,l1,l2,l3};
      Ahi[kt] = bitcast<bf16x8>(th);
      Alo[kt] = bitcast<bf16x8>(tl);
    }
  }

  // bias / w_hx per C/D reg: m = 16*wv + 4*g + r
  f32x4 bh, wx;
  #pragma unroll
  for (int r = 0; r < 4; ++r) {
    const int m = wv*16 + 4*g + r;
    bh[r] = b_h[m];
    wx[r] = w_hx[m];
  }

  // x stream for this lane's batch column (all waves share the 16 cols)
  const float* px = x + (size_t)(n0 + l15) * RNN_T;
  f32x4 xc = *(const f32x4*)px;

  const f32x4 ZV = {0.0f, 0.0f, 0.0f, 0.0f};
  u32x2 ownHi = {0u, 0u}, ownLo = {0u, 0u};   // own j-half of h(t), h(0)=0

  __syncthreads();

  for (int t4 = 0; t4 < RNN_T/4; ++t4) {
    f32x4 xn = xc;
    if (t4 + 1 < RNN_T/4) xn = *(const f32x4*)(px + 4*t4 + 4);
    #pragma unroll
    for (int q = 0; q < 4; ++q) {
      const int rb = q & 1;        // t = 4*t4+q, rb = t&1
      const int wb = rb ^ 1;

      // ---- B-fragments: own kt from regs + partner b64; others full b128 ----
      bf16x8 Bhi[4], Blo[4];
      #pragma unroll
      for (int kt = 0; kt < 4; ++kt) {
        if (kt == ownkt) {   // wave-uniform branch
          const char* phc = (const char*)&hbuf[rb][0][kt][lane] + (ownhalf^1)*8;
          const char* plc = (const char*)&hbuf[rb][1][kt][lane] + (ownhalf^1)*8;
          const u32x2 pH = *(const u32x2*)phc;
          const u32x2 pL = *(const u32x2*)plc;
          u32x4 vH, vL;
          if (ownhalf == 0) {
            vH = u32x4{ownHi[0], ownHi[1], pH[0], pH[1]};
            vL = u32x4{ownLo[0], ownLo[1], pL[0], pL[1]};
          } else {
            vH = u32x4{pH[0], pH[1], ownHi[0], ownHi[1]};
            vL = u32x4{pL[0], pL[1], ownLo[0], ownLo[1]};
          }
          Bhi[kt] = bitcast<bf16x8>(vH);
          Blo[kt] = bitcast<bf16x8>(vL);
        } else {
          Bhi[kt] = hbuf[rb][0][kt][lane];
          Blo[kt] = hbuf[rb][1][kt][lane];
        }
      }

      // ---- 12 MFMAs: 3 independent chains of depth 4 ----
      f32x4 c0, c1, c2;
      const float xv = xc[q];
      #pragma unroll
      for (int r = 0; r < 4; ++r) c0[r] = __builtin_fmaf(wx[r], xv, bh[r]);
      __builtin_amdgcn_s_setprio(1);
      #pragma unroll
      for (int kt = 0; kt < 4; ++kt) {
        c0 = mfma16(Ahi[kt], Bhi[kt], c0);
        c1 = mfma16(Alo[kt], Bhi[kt], kt ? c1 : ZV);
        c2 = mfma16(Ahi[kt], Blo[kt], kt ? c2 : ZV);
      }
      __builtin_amdgcn_s_setprio(0);

      // ---- epilogue: merge, tanh, trunc-hi/RNE-lo split (4 values) ----
      const float v0 = (c0[0] + c1[0]) + c2[0];
      const float v1 = (c0[1] + c1[1]) + c2[1];
      const float v2 = (c0[2] + c1[2]) + c2[2];
      const float v3 = (c0[3] + c1[3]) + c2[3];
      const float t0 = fast_tanh(v0), t1 = fast_tanh(v1);
      const float t2 = fast_tanh(v2), t3 = fast_tanh(v3);
      const unsigned u0 = __float_as_uint(t0), u1 = __float_as_uint(t1);
      const unsigned u2 = __float_as_uint(t2), u3 = __float_as_uint(t3);
      const unsigned h01 = (u1 & 0xffff0000u) | (u0 >> 16);  // trunc-bf16 pack
      const unsigned h23 = (u3 & 0xffff0000u) | (u2 >> 16);
      const float e0 = t0 - __uint_as_float(h01 << 16);       // exact residuals
      const float e1 = t1 - __uint_as_float(h01 & 0xffff0000u);
      const float e2 = t2 - __uint_as_float(h23 << 16);
      const float e3 = t3 - __uint_as_float(h23 & 0xffff0000u);
      ownHi = u32x2{h01, h23};
      ownLo = u32x2{pk_bf16(e0, e1), pk_bf16(e2, e3)};

      // write own j-half of B-slot (kt = ownkt) for the next step
      *(u32x2*)((char*)&hbuf[wb][0][ownkt][lane] + ownhalf*8) = ownHi;
      *(u32x2*)((char*)&hbuf[wb][1][ownkt][lane] + ownhalf*8) = ownLo;
      BAR();
    }
    xc = xn;
  }

  // ---- projection: out[b][c] = w_ph[c,:] . h_last[:,b] + b_p[c] ----
  // t=2047 wrote wb=0 -> h(T) is in buffer 0.
  {
    const int c = tid >> 4;
    const int n = tid & 15;
    if (c < RNN_C) {
      float sum = b_p[c];
      for (int k = 0; k < RNN_H; ++k) {
        const int kt = k >> 5;
        const int l  = 16*((k & 15) >> 2) + n;
        const int j  = (k & 3) + 4*((k >> 4) & 1);
        const unsigned short* ph = (const unsigned short*)&hbuf[0][0][kt][l];
        const unsigned short* pl = (const unsigned short*)&hbuf[0][1][kt][l];
        const float hv = __uint_as_float(((unsigned)ph[j]) << 16)
                       + __uint_as_float(((unsigned)pl[j]) << 16);
        sum = __builtin_fmaf(w_ph[c*RNN_H + k], hv, sum);
      }
      out[(size_t)(n0 + n)*RNN_C + c] = sum;
    }
  }
}

extern "C" void kernel_launch(void* const* d_in, const int* in_sizes, int n_in,
                              void* d_out, int out_size, void* d_ws, size_t ws_size,
                              hipStream_t stream) {
  (void)in_sizes; (void)n_in; (void)out_size; (void)d_ws; (void)ws_size;
  const float* x    = (const float*)d_in[0];
  const float* w_hx = (const float*)d_in[1];
  const float* w_hh = (const float*)d_in[2];
  const float* b_h  = (const float*)d_in[3];
  const float* w_ph = (const float*)d_in[4];
  const float* b_p  = (const float*)d_in[5];
  float* out = (float*)d_out;
  rnn_fused<<<dim3(RNN_B/BLK_N), dim3(512), 0, stream>>>(x, w_hx, w_hh, b_h, w_ph, b_p, out);
}

// Round 8
// 1791.133 us; speedup vs baseline: 1.3504x; 1.0160x over previous
//
#include <hip/hip_runtime.h>
#include <hip/hip_bf16.h>

typedef short    bf16x8 __attribute__((ext_vector_type(8)));
typedef float    f32x4  __attribute__((ext_vector_type(4)));
typedef unsigned u32x4  __attribute__((ext_vector_type(4)));

#define RNN_H 128
#define RNN_T 2048
#define RNN_B 8192
#define RNN_C 10
#define BLK_N 16

template <typename D, typename S>
__device__ __forceinline__ D bitcast(const S& s) {
  static_assert(sizeof(D) == sizeof(S), "size mismatch");
  D d; __builtin_memcpy(&d, &s, sizeof(D)); return d;
}

__device__ __forceinline__ unsigned pk_bf16(float a0, float a1) {
  __hip_bfloat162 b2 = __float22bfloat162_rn(make_float2(a0, a1));
  unsigned u; __builtin_memcpy(&u, &b2, 4);
  return u;  // a0 in low 16, a1 in high 16
}

// setup-time RNE split for W: a ~= hi + lo, residual ~2^-17 |a|
__device__ __forceinline__ void split2(float a0, float a1, unsigned &hp, unsigned &lp) {
  hp = pk_bf16(a0, a1);
  float h0 = __uint_as_float(hp << 16);
  float h1 = __uint_as_float(hp & 0xffff0000u);
  lp = pk_bf16(a0 - h0, a1 - h1);
}

__device__ __forceinline__ float fast_tanh(float a) {
  // tanh(a) = 1 - 2/(exp(2a)+1)
  float e = __builtin_amdgcn_exp2f(a * 2.885390081777927f);
  return 1.0f - 2.0f * __builtin_amdgcn_rcpf(e + 1.0f);
}

__device__ __forceinline__ f32x4 mfma16(bf16x8 a, bf16x8 b, f32x4 c) {
  return __builtin_amdgcn_mfma_f32_16x16x32_bf16(a, b, c, 0, 0, 0);
}

// k-bijection for 16x16x32 frags (same map for A-load and B-store, so the true
// HW k-layout cancels): slot (g = lane>>4, j) -> k = 32*kt + 4*g + (j&3) + 16*(j>>2).
// Wave wv owns rows [64*wv, 64*wv+64) = k-slots 2*wv, 2*wv+1. Its C/D regs
// (mt, r) map to slot 2*wv + (mt>>1), j = (r) + 4*(mt&1) -> the packed epilogue
// output IS the next step's own B-fragment: register recycle, no LDS for half
// the k-range. Only the partner wave's 2 slots (4 x b128) come from LDS.

// LDS-only barrier: drain ds ops, never vmcnt (x prefetch stays in flight).
#define BAR() asm volatile("s_waitcnt lgkmcnt(0)\n\ts_barrier" ::: "memory")

__global__ __launch_bounds__(128, 1)
void rnn_fused(const float* __restrict__ x, const float* __restrict__ w_hx,
               const float* __restrict__ w_hh, const float* __restrict__ b_h,
               const float* __restrict__ w_ph, const float* __restrict__ b_p,
               float* __restrict__ out)
{
  // h double-buffered, B-frag order: [buf][hi/lo][slot(4)][lane(64)]. 16 KiB.
  __shared__ bf16x8 hbuf[2][2][4][64];

  const int tid  = threadIdx.x;
  const int lane = tid & 63;
  const int wv   = tid >> 6;         // 0..1: rows [64*wv, 64*wv+64)
  const int g    = lane >> 4;
  const int l15  = lane & 15;
  const int n0   = blockIdx.x * BLK_N;
  const int own0 = 2*wv, own1 = 2*wv + 1;       // own k-slots
  const int par0 = 2 - 2*wv, par1 = 3 - 2*wv;   // partner k-slots

  { // zero h(0) = buffer 0
    bf16x8 z = {0,0,0,0,0,0,0,0};
    bf16x8* p = &hbuf[0][0][0][0];
    #pragma unroll
    for (int i = 0; i < 4; ++i) p[tid + 128*i] = z;
  }

  // ---- W_hh hi/lo A-fragments for this wave's 64 rows (128 VGPRs) ----
  // index i: 0,1 = own slots (global kt 2wv, 2wv+1), 2,3 = partner slots.
  bf16x8 Ahi[4][4], Alo[4][4];
  #pragma unroll
  for (int mt = 0; mt < 4; ++mt) {
    const float* wrow = w_hh + (size_t)(wv*64 + mt*16 + l15)*RNN_H + 4*g;
    #pragma unroll
    for (int i = 0; i < 4; ++i) {
      const int ktg = (2*wv + i) & 3;
      f32x4 w0 = *(const f32x4*)(wrow + ktg*32);        // j=0..3 (k off 0..3)
      f32x4 w1 = *(const f32x4*)(wrow + ktg*32 + 16);   // j=4..7 (k off 16..19)
      unsigned h0,h1,h2,h3,l0,l1,l2,l3;
      split2(w0[0], w0[1], h0, l0);
      split2(w0[2], w0[3], h1, l1);
      split2(w1[0], w1[1], h2, l2);
      split2(w1[2], w1[3], h3, l3);
      u32x4 th = {h0,h1,h2,h3}, tl = {l0,l1,l2,l3};
      Ahi[mt][i] = bitcast<bf16x8>(th);
      Alo[mt][i] = bitcast<bf16x8>(tl);
    }
  }

  // bias / w_hx per C/D reg: m = 64*wv + 16*mt + 4*g + r
  f32x4 bh[4], wx[4];
  #pragma unroll
  for (int mt = 0; mt < 4; ++mt)
    #pragma unroll
    for (int r = 0; r < 4; ++r) {
      const int m = wv*64 + mt*16 + 4*g + r;
      bh[mt][r] = b_h[m];
      wx[mt][r] = w_hx[m];
    }

  // x stream for this lane's batch column (both waves share the 16 cols)
  const float* px = x + (size_t)(n0 + l15) * RNN_T;
  f32x4 xc = *(const f32x4*)px;

  const f32x4 ZV = {0.0f, 0.0f, 0.0f, 0.0f};
  // own h fragments (slots own0, own1; hi and lo), h(0) = 0
  u32x4 oHA = {0,0,0,0}, oHB = {0,0,0,0}, oLA = {0,0,0,0}, oLB = {0,0,0,0};

  __syncthreads();

// epilogue for row-tile mt: merge chains, tanh, trunc-hi / RNE-lo split
#define EPI(mt)                                                              \
  {                                                                          \
    const float v0 = (c0[mt][0] + c1[mt][0]) + c2[mt][0];                    \
    const float v1 = (c0[mt][1] + c1[mt][1]) + c2[mt][1];                    \
    const float v2 = (c0[mt][2] + c1[mt][2]) + c2[mt][2];                    \
    const float v3 = (c0[mt][3] + c1[mt][3]) + c2[mt][3];                    \
    const float t0 = fast_tanh(v0), t1 = fast_tanh(v1);                     \
    const float t2 = fast_tanh(v2), t3 = fast_tanh(v3);                     \
    const unsigned u0 = __float_as_uint(t0), u1 = __float_as_uint(t1);       \
    const unsigned u2 = __float_as_uint(t2), u3 = __float_as_uint(t3);       \
    const unsigned h01 = (u1 & 0xffff0000u) | (u0 >> 16);                    \
    const unsigned h23 = (u3 & 0xffff0000u) | (u2 >> 16);                    \
    const float e0 = t0 - __uint_as_float(h01 << 16);                        \
    const float e1 = t1 - __uint_as_float(h01 & 0xffff0000u);                \
    const float e2 = t2 - __uint_as_float(h23 << 16);                        \
    const float e3 = t3 - __uint_as_float(h23 & 0xffff0000u);                \
    nh[2*(mt)] = h01; nh[2*(mt)+1] = h23;                                    \
    nl[2*(mt)] = pk_bf16(e0, e1); nl[2*(mt)+1] = pk_bf16(e2, e3);            \
  }

// 3 MFMAs on partner slot par1 for row-tile mt
#define MF3(mt)                                                              \
  c0[mt] = mfma16(Ahi[mt][3], PH1, c0[mt]);                                  \
  c1[mt] = mfma16(Alo[mt][3], PH1, c1[mt]);                                  \
  c2[mt] = mfma16(Ahi[mt][3], PL1, c2[mt]);

  for (int t4 = 0; t4 < RNN_T/4; ++t4) {
    f32x4 xn = xc;
    if (t4 + 1 < RNN_T/4) xn = *(const f32x4*)(px + 4*t4 + 4);
    #pragma unroll
    for (int q = 0; q < 4; ++q) {
      const int rb = q & 1;        // t = 4*t4+q, rb = t&1
      const int wb = rb ^ 1;

      // stage partner slots (4 x ds_read_b128, conflict-free) — issued first;
      // compiler gates first USE with counted lgkmcnt, so the 24 own-slot
      // MFMAs below run with zero LDS wait and fully cover the drain.
      const bf16x8 PH0 = hbuf[rb][0][par0][lane];
      const bf16x8 PL0 = hbuf[rb][1][par0][lane];
      const bf16x8 PH1 = hbuf[rb][0][par1][lane];
      const bf16x8 PL1 = hbuf[rb][1][par1][lane];

      const bf16x8 oBhA = bitcast<bf16x8>(oHA), oBhB = bitcast<bf16x8>(oHB);
      const bf16x8 oBlA = bitcast<bf16x8>(oLA), oBlB = bitcast<bf16x8>(oLB);

      const float xv = xc[q];
      f32x4 c0[4], c1[4], c2[4];

      // own-slot MFMAs: 6 per mt, 24 total, B operands from registers
      #pragma unroll
      for (int mt = 0; mt < 4; ++mt) {
        #pragma unroll
        for (int r = 0; r < 4; ++r)
          c0[mt][r] = __builtin_fmaf(wx[mt][r], xv, bh[mt][r]);
        c0[mt] = mfma16(Ahi[mt][0], oBhA, c0[mt]);
        c0[mt] = mfma16(Ahi[mt][1], oBhB, c0[mt]);
        c1[mt] = mfma16(Alo[mt][0], oBhA, ZV);
        c1[mt] = mfma16(Alo[mt][1], oBhB, c1[mt]);
        c2[mt] = mfma16(Ahi[mt][0], oBlA, ZV);
        c2[mt] = mfma16(Ahi[mt][1], oBlB, c2[mt]);
      }
      // partner slot par0: 12 MFMAs
      #pragma unroll
      for (int mt = 0; mt < 4; ++mt) {
        c0[mt] = mfma16(Ahi[mt][2], PH0, c0[mt]);
        c1[mt] = mfma16(Alo[mt][2], PH0, c1[mt]);
        c2[mt] = mfma16(Ahi[mt][2], PL0, c2[mt]);
      }
      // partner slot par1 interleaved with per-mt epilogue: epi(mt) issues
      // after mf3(mt+1), so its VALU co-issues under later MFMAs (in-order,
      // intra-wave, no cross-wave dependence).
      unsigned nh[8], nl[8];
      MF3(0)
      MF3(1)
      EPI(0)
      MF3(2)
      EPI(1)
      MF3(3)
      EPI(2)
      EPI(3)

      oHA = u32x4{nh[0], nh[1], nh[2], nh[3]};
      oHB = u32x4{nh[4], nh[5], nh[6], nh[7]};
      oLA = u32x4{nl[0], nl[1], nl[2], nl[3]};
      oLB = u32x4{nl[4], nl[5], nl[6], nl[7]};

      // publish own slots for the partner wave (4 x ds_write_b128)
      hbuf[wb][0][own0][lane] = bitcast<bf16x8>(oHA);
      hbuf[wb][0][own1][lane] = bitcast<bf16x8>(oHB);
      hbuf[wb][1][own0][lane] = bitcast<bf16x8>(oLA);
      hbuf[wb][1][own1][lane] = bitcast<bf16x8>(oLB);
      BAR();
    }
    xc = xn;
  }

  __syncthreads();

  // ---- projection: out[b][c] = w_ph[c,:] . h_last[:,b] + b_p[c] ----
  // t=2047 wrote buffer 0 -> h(T) in hbuf[0].
  #pragma unroll
  for (int pass = 0; pass < 2; ++pass) {
    const int idx = tid + pass*128;
    const int c = idx >> 4;
    const int n = idx & 15;
    if (c < RNN_C) {
      float sum = b_p[c];
      for (int k = 0; k < RNN_H; ++k) {
        const int kt = k >> 5;
        const int l  = 16*((k & 15) >> 2) + n;
        const int j  = (k & 3) + 4*((k >> 4) & 1);
        const unsigned short* ph = (const unsigned short*)&hbuf[0][0][kt][l];
        const unsigned short* pl = (const unsigned short*)&hbuf[0][1][kt][l];
        const float hv = __uint_as_float(((unsigned)ph[j]) << 16)
                       + __uint_as_float(((unsigned)pl[j]) << 16);
        sum = __builtin_fmaf(w_ph[c*RNN_H + k], hv, sum);
      }
      out[(size_t)(n0 + n)*RNN_C + c] = sum;
    }
  }
}

extern "C" void kernel_launch(void* const* d_in, const int* in_sizes, int n_in,
                              void* d_out, int out_size, void* d_ws, size_t ws_size,
                              hipStream_t stream) {
  (void)in_sizes; (void)n_in; (void)out_size; (void)d_ws; (void)ws_size;
  const float* x    = (const float*)d_in[0];
  const float* w_hx = (const float*)d_in[1];
  const float* w_hh = (const float*)d_in[2];
  const float* b_h  = (const float*)d_in[3];
  const float* w_ph = (const float*)d_in[4];
  const float* b_p  = (const float*)d_in[5];
  float* out = (float*)d_out;
  rnn_fused<<<dim3(RNN_B/BLK_N), dim3(128), 0, stream>>>(x, w_hx, w_hh, b_h, w_ph, b_p, out);
}

// Round 9
// 1496.789 us; speedup vs baseline: 1.6160x; 1.1967x over previous
//
#include <hip/hip_runtime.h>
#include <hip/hip_bf16.h>

typedef short    bf16x8 __attribute__((ext_vector_type(8)));
typedef float    f32x4  __attribute__((ext_vector_type(4)));
typedef unsigned u32x4  __attribute__((ext_vector_type(4)));

#define RNN_H 128
#define RNN_T 2048
#define RNN_B 8192
#define RNN_C 10
#define BLK_N 16

template <typename D, typename S>
__device__ __forceinline__ D bitcast(const S& s) {
  static_assert(sizeof(D) == sizeof(S), "size mismatch");
  D d; __builtin_memcpy(&d, &s, sizeof(D)); return d;
}

__device__ __forceinline__ unsigned pk_bf16(float a0, float a1) {
  __hip_bfloat162 b2 = __float22bfloat162_rn(make_float2(a0, a1));
  unsigned u; __builtin_memcpy(&u, &b2, 4);
  return u;  // a0 in low 16, a1 in high 16
}

// setup-time RNE split for W: a ~= hi + lo, residual ~2^-17 |a|
__device__ __forceinline__ void split2(float a0, float a1, unsigned &hp, unsigned &lp) {
  hp = pk_bf16(a0, a1);
  float h0 = __uint_as_float(hp << 16);
  float h1 = __uint_as_float(hp & 0xffff0000u);
  lp = pk_bf16(a0 - h0, a1 - h1);
}

__device__ __forceinline__ float fast_tanh(float a) {
  // tanh(a) = 1 - 2/(exp(2a)+1)
  float e = __builtin_amdgcn_exp2f(a * 2.885390081777927f);
  return 1.0f - 2.0f * __builtin_amdgcn_rcpf(e + 1.0f);
}

__device__ __forceinline__ f32x4 mfma16(bf16x8 a, bf16x8 b, f32x4 c) {
  return __builtin_amdgcn_mfma_f32_16x16x32_bf16(a, b, c, 0, 0, 0);
}

// k-bijection for 16x16x32 frags (same map for A-load and B-store, so the true
// HW k-layout cancels): slot s covers k in [32s,32s+32); within the slot,
// lane group g = lane>>4, j = 0..7 -> k = 32s + 4g + (j&3) + 16*(j>>2).
// Wave wv owns rows [32wv, 32wv+32) == ALL of slot s = wv. Its C/D regs
// (mt in 0..1, r) map to j = r + 4*mt of slot wv -> the packed epilogue output
// IS next step's own B-fragment (register recycle). Only the 3 partner slots
// (3 x 2 ds_read_b128) come from LDS; 2 ds_write_b128 publish our slot.

// LDS-only barrier: drain ds ops, never vmcnt (x prefetch stays in flight).
#define BAR() asm volatile("s_waitcnt lgkmcnt(0)\n\ts_barrier" ::: "memory")
// pin memory-op program positions (spread LDS issue; VALU/MFMA still float)
#define MEMPIN() asm volatile("" ::: "memory")

__global__ __launch_bounds__(256, 2)
void rnn_fused(const float* __restrict__ x, const float* __restrict__ w_hx,
               const float* __restrict__ w_hh, const float* __restrict__ b_h,
               const float* __restrict__ w_ph, const float* __restrict__ b_p,
               float* __restrict__ out)
{
  // h double-buffered, B-frag order: [buf][hi/lo][slot(4)][lane(64)]. 16 KiB.
  __shared__ u32x4 hbuf[2][2][4][64];

  const int tid  = threadIdx.x;
  const int lane = tid & 63;
  const int wv   = tid >> 6;         // 0..3: rows [32wv, 32wv+32) = slot wv
  const int g    = lane >> 4;
  const int l15  = lane & 15;
  const int n0   = blockIdx.x * BLK_N;
  const int pa = (wv+1)&3, pb = (wv+2)&3, pc = (wv+3)&3;  // partner slots

  { // zero h(0) = buffer 0 (2*4*64 = 512 entries, 256 threads)
    u32x4 z = {0,0,0,0};
    u32x4* p = &hbuf[0][0][0][0];
    p[tid] = z; p[tid + 256] = z;
  }

  // ---- W_hh hi/lo A-fragments, indexed by READ ORDER i (compile-time):
  // i=0 own slot (wv), i=1,2,3 partner slots (wv+i)&3. 64 VGPRs.
  bf16x8 Ahi[2][4], Alo[2][4];
  #pragma unroll
  for (int mt = 0; mt < 2; ++mt) {
    const float* wrow = w_hh + (size_t)(wv*32 + mt*16 + l15)*RNN_H + 4*g;
    #pragma unroll
    for (int i = 0; i < 4; ++i) {
      const int s = (wv + i) & 3;          // global slot (runtime addr is fine)
      f32x4 w0 = *(const f32x4*)(wrow + s*32);        // j=0..3 (k off 0..3)
      f32x4 w1 = *(const f32x4*)(wrow + s*32 + 16);   // j=4..7 (k off 16..19)
      unsigned h0,h1,h2,h3,l0,l1,l2,l3;
      split2(w0[0], w0[1], h0, l0);
      split2(w0[2], w0[3], h1, l1);
      split2(w1[0], w1[1], h2, l2);
      split2(w1[2], w1[3], h3, l3);
      u32x4 th = {h0,h1,h2,h3}, tl = {l0,l1,l2,l3};
      Ahi[mt][i] = bitcast<bf16x8>(th);
      Alo[mt][i] = bitcast<bf16x8>(tl);
    }
  }

  // bias / w_hx per C/D reg: m = 32wv + 16mt + 4g + r
  f32x4 bh[2], wx[2];
  #pragma unroll
  for (int mt = 0; mt < 2; ++mt)
    #pragma unroll
    for (int r = 0; r < 4; ++r) {
      const int m = wv*32 + mt*16 + 4*g + r;
      bh[mt][r] = b_h[m];
      wx[mt][r] = w_hx[m];
    }

  // x stream for this lane's batch column
  const float* px = x + (size_t)(n0 + l15) * RNN_T;
  f32x4 xc = *(const f32x4*)px;

  const f32x4 ZV = {0.0f, 0.0f, 0.0f, 0.0f};
  u32x4 oH = {0,0,0,0}, oL = {0,0,0,0};   // own slot frags (h(0) = 0)

  __syncthreads();

  for (int t4 = 0; t4 < RNN_T/4; ++t4) {
    f32x4 xn = xc;
    if (t4 + 1 < RNN_T/4) xn = *(const f32x4*)(px + 4*t4 + 4);
    #pragma unroll
    for (int q = 0; q < 4; ++q) {
      const int rb = q & 1;        // t = 4*t4+q; rb = t&1
      const int wb = rb ^ 1;
      const float xv = xc[q];

      // partner slot a reads issued first, then own-slot MFMAs (register-fed)
      // cover the LDS latency; reads b, c staggered to spread the LDS pipe.
      const u32x4 aH = hbuf[rb][0][pa][lane];
      const u32x4 aL = hbuf[rb][1][pa][lane];
      MEMPIN();

      f32x4 c0[2], c1[2], c2[2];
      #pragma unroll
      for (int mt = 0; mt < 2; ++mt)
        #pragma unroll
        for (int r = 0; r < 4; ++r)
          c0[mt][r] = __builtin_fmaf(wx[mt][r], xv, bh[mt][r]);

      const bf16x8 oBh = bitcast<bf16x8>(oH), oBl = bitcast<bf16x8>(oL);
      __builtin_amdgcn_s_setprio(1);
      // i=0: own slot, B from registers (6 MFMAs)
      #pragma unroll
      for (int mt = 0; mt < 2; ++mt) {
        c0[mt] = mfma16(Ahi[mt][0], oBh, c0[mt]);
        c1[mt] = mfma16(Alo[mt][0], oBh, ZV);
        c2[mt] = mfma16(Ahi[mt][0], oBl, ZV);
      }
      const u32x4 bH = hbuf[rb][0][pb][lane];
      const u32x4 bL = hbuf[rb][1][pb][lane];
      MEMPIN();
      // i=1: partner a
      {
        const bf16x8 BH = bitcast<bf16x8>(aH), BL = bitcast<bf16x8>(aL);
        #pragma unroll
        for (int mt = 0; mt < 2; ++mt) {
          c0[mt] = mfma16(Ahi[mt][1], BH, c0[mt]);
          c1[mt] = mfma16(Alo[mt][1], BH, c1[mt]);
          c2[mt] = mfma16(Ahi[mt][1], BL, c2[mt]);
        }
      }
      const u32x4 cH = hbuf[rb][0][pc][lane];
      const u32x4 cL = hbuf[rb][1][pc][lane];
      MEMPIN();
      // i=2: partner b
      {
        const bf16x8 BH = bitcast<bf16x8>(bH), BL = bitcast<bf16x8>(bL);
        #pragma unroll
        for (int mt = 0; mt < 2; ++mt) {
          c0[mt] = mfma16(Ahi[mt][2], BH, c0[mt]);
          c1[mt] = mfma16(Alo[mt][2], BH, c1[mt]);
          c2[mt] = mfma16(Ahi[mt][2], BL, c2[mt]);
        }
      }
      // i=3: partner c
      {
        const bf16x8 BH = bitcast<bf16x8>(cH), BL = bitcast<bf16x8>(cL);
        #pragma unroll
        for (int mt = 0; mt < 2; ++mt) {
          c0[mt] = mfma16(Ahi[mt][3], BH, c0[mt]);
          c1[mt] = mfma16(Alo[mt][3], BH, c1[mt]);
          c2[mt] = mfma16(Ahi[mt][3], BL, c2[mt]);
        }
      }
      __builtin_amdgcn_s_setprio(0);

      // epilogue: merge chains, tanh, trunc-hi/RNE-lo split; pack own frags.
      unsigned nh[4], nl[4];
      #pragma unroll
      for (int mt = 0; mt < 2; ++mt) {
        const float v0 = (c0[mt][0] + c1[mt][0]) + c2[mt][0];
        const float v1 = (c0[mt][1] + c1[mt][1]) + c2[mt][1];
        const float v2 = (c0[mt][2] + c1[mt][2]) + c2[mt][2];
        const float v3 = (c0[mt][3] + c1[mt][3]) + c2[mt][3];
        const float t0 = fast_tanh(v0), t1 = fast_tanh(v1);
        const float t2 = fast_tanh(v2), t3 = fast_tanh(v3);
        const unsigned u0 = __float_as_uint(t0), u1 = __float_as_uint(t1);
        const unsigned u2 = __float_as_uint(t2), u3 = __float_as_uint(t3);
        const unsigned h01 = (u1 & 0xffff0000u) | (u0 >> 16);  // trunc pack
        const unsigned h23 = (u3 & 0xffff0000u) | (u2 >> 16);
        const float e0 = t0 - __uint_as_float(h01 << 16);      // exact resid
        const float e1 = t1 - __uint_as_float(h01 & 0xffff0000u);
        const float e2 = t2 - __uint_as_float(h23 << 16);
        const float e3 = t3 - __uint_as_float(h23 & 0xffff0000u);
        nh[2*mt] = h01; nh[2*mt+1] = h23;
        nl[2*mt] = pk_bf16(e0, e1); nl[2*mt+1] = pk_bf16(e2, e3);
      }
      oH = u32x4{nh[0], nh[1], nh[2], nh[3]};
      oL = u32x4{nl[0], nl[1], nl[2], nl[3]};

      // publish own slot for the other 3 waves (2 x ds_write_b128)
      hbuf[wb][0][wv][lane] = oH;
      hbuf[wb][1][wv][lane] = oL;
      BAR();
    }
    xc = xn;
  }

  __syncthreads();

  // ---- projection: out[b][c] = w_ph[c,:] . h_last[:,b] + b_p[c] ----
  // t=2047 wrote buffer 0 -> h(T) in hbuf[0].
  {
    const int c = tid >> 4;
    const int n = tid & 15;
    if (c < RNN_C) {
      float sum = b_p[c];
      for (int k = 0; k < RNN_H; ++k) {
        const int s  = k >> 5;
        const int l  = 16*((k & 15) >> 2) + n;
        const int j  = (k & 3) + 4*((k >> 4) & 1);
        const unsigned short* ph = (const unsigned short*)&hbuf[0][0][s][l];
        const unsigned short* pl = (const unsigned short*)&hbuf[0][1][s][l];
        const float hv = __uint_as_float(((unsigned)ph[j]) << 16)
                       + __uint_as_float(((unsigned)pl[j]) << 16);
        sum = __builtin_fmaf(w_ph[c*RNN_H + k], hv, sum);
      }
      out[(size_t)(n0 + n)*RNN_C + c] = sum;
    }
  }
}

extern "C" void kernel_launch(void* const* d_in, const int* in_sizes, int n_in,
                              void* d_out, int out_size, void* d_ws, size_t ws_size,
                              hipStream_t stream) {
  (void)in_sizes; (void)n_in; (void)out_size; (void)d_ws; (void)ws_size;
  const float* x    = (const float*)d_in[0];
  const float* w_hx = (const float*)d_in[1];
  const float* w_hh = (const float*)d_in[2];
  const float* b_h  = (const float*)d_in[3];
  const float* w_ph = (const float*)d_in[4];
  const float* b_p  = (const float*)d_in[5];
  float* out = (float*)d_out;
  rnn_fused<<<dim3(RNN_B/BLK_N), dim3(256), 0, stream>>>(x, w_hx, w_hh, b_h, w_ph, b_p, out);
}

// Round 10
// 1406.931 us; speedup vs baseline: 1.7192x; 1.0639x over previous
//
#include <hip/hip_runtime.h>
#include <hip/hip_bf16.h>

typedef int      i32x4 __attribute__((ext_vector_type(4)));
typedef float    f32x4 __attribute__((ext_vector_type(4)));
typedef unsigned u32x2 __attribute__((ext_vector_type(2)));

#define RNN_H 128
#define RNN_T 2048
#define RNN_B 8192
#define RNN_C 10
#define BLK_N 16
#define QSF 32512.0f   // 127*256: 15-bit fixed-point scale for h and W

// LDS-only barrier: drain ds ops, never vmcnt (x prefetch stays in flight).
#define BAR() asm volatile("s_waitcnt lgkmcnt(0)\n\ts_barrier" ::: "memory")
#define MEMPIN() asm volatile("" ::: "memory")

__device__ __forceinline__ i32x4 mfma_i8(i32x4 a, i32x4 b, i32x4 c) {
  return __builtin_amdgcn_mfma_i32_16x16x64_i8(a, b, c, 0, 0, 0);
}

// k-bijection for 16x16x64 i8 frags (byte j of the 4-reg operand, lane group
// g = lane>>4): k = 64*slot + 4g + (j&3) + 16*(j>>2). Same map for A-fill and
// B-fill, so the HW's internal layout cancels (verified pattern from the bf16
// rounds). Wave wv owns rows [32wv,32wv+32) = half 'hw' (j-range 8hw..8hw+7 =
// regs 2hw..2hw+1) of slot sw = wv>>1: its C/D output (row = 32wv+16mt+4g+r at
// lane (g,l15)) packs bit-exactly into B-frag byte j = 8hw+4mt+r at the same
// lane -> register recycle; only 6 b64 LDS reads + 2 b64 writes per step.

__global__ __launch_bounds__(256, 2)
void rnn_fused(const float* __restrict__ x, const float* __restrict__ w_hx,
               const float* __restrict__ w_hh, const float* __restrict__ b_h,
               const float* __restrict__ w_ph, const float* __restrict__ b_p,
               float* __restrict__ out)
{
  // h double-buffered: [buf][slot(2)][part a/b][half(2)][lane(64)] x 8B = 8 KiB
  __shared__ u32x2 hbuf[2][2][2][2][64];
  __shared__ float rs[128];   // per-row W scales for C/D-lane redistribution

  const int tid  = threadIdx.x;
  const int lane = tid & 63;
  const int wv   = tid >> 6;       // 0..3: rows [32wv, 32wv+32)
  const int g    = lane >> 4;
  const int l15  = lane & 15;
  const int n0   = blockIdx.x * BLK_N;
  const int sw = wv >> 1, hw = wv & 1, so = sw ^ 1;

  { // zero h(0) = buffer 0 (512 u32x2 entries)
    u32x2 z = {0u, 0u};
    u32x2* p = &hbuf[0][0][0][0][0];
    p[tid] = z; p[tid + 256] = z;
  }

  // ---- W quantization: per-row 15-bit fixed point, split to int8 (wa, wb) ----
  i32x4 WA[2][2], WB[2][2];   // [mt][slot-order: 0 = own slot, 1 = other]
  float rm[2];
  #pragma unroll
  for (int mt = 0; mt < 2; ++mt) {
    const float* wrow = w_hh + (size_t)(wv*32 + mt*16 + l15)*RNN_H + 4*g;
    float vals[2][4][4];
    float mx = 0.0f;
    #pragma unroll
    for (int li = 0; li < 2; ++li) {
      const int s = li ? so : sw;
      #pragma unroll
      for (int i = 0; i < 4; ++i) {
        f32x4 v = *(const f32x4*)(wrow + s*64 + i*16);   // k = 64s + 16i + 4g + r
        #pragma unroll
        for (int r = 0; r < 4; ++r) { vals[li][i][r] = v[r]; mx = fmaxf(mx, fabsf(v[r])); }
      }
    }
    mx = fmaxf(mx, __shfl_xor(mx, 16));   // combine the 4 g-lanes of this row
    mx = fmaxf(mx, __shfl_xor(mx, 32));
    const float inv = (mx > 0.0f) ? (QSF / mx) : 0.0f;
    rm[mt] = mx * (1.0f / QSF);
    #pragma unroll
    for (int li = 0; li < 2; ++li)
      #pragma unroll
      for (int i = 0; i < 4; ++i) {
        unsigned pa = 0, pb = 0;
        #pragma unroll
        for (int r = 0; r < 4; ++r) {
          const int Wq  = (int)rintf(vals[li][i][r] * inv);  // |Wq| <= 32512
          const int wa  = (Wq + 128) >> 8;                   // [-127, 127]
          const int wbv = Wq - (wa << 8);                    // [-128, 127]
          pa |= ((unsigned)(wa  & 255)) << (8*r);
          pb |= ((unsigned)(wbv & 255)) << (8*r);
        }
        WA[mt][li][i] = (int)pa;
        WB[mt][li][i] = (int)pb;
      }
  }

  if (g == 0) {                       // publish row scales (rows 32wv+16mt+l15)
    rs[wv*32 +  0 + l15] = rm[0];
    rs[wv*32 + 16 + l15] = rm[1];
  }
  __syncthreads();

  // per-C/D-reg constants: m = 32wv + 16mt + 4g + r
  f32x4 kk[2], wx[2], bh[2];
  #pragma unroll
  for (int mt = 0; mt < 2; ++mt)
    #pragma unroll
    for (int r = 0; r < 4; ++r) {
      const int m = wv*32 + mt*16 + 4*g + r;
      kk[mt][r] = rs[m] * (1.0f/127.0f);   // pre = kk * ((P1<<8)+P2+P3) + xb
      wx[mt][r] = w_hx[m];
      bh[mt][r] = b_h[m];
    }

  const float* px = x + (size_t)(n0 + l15) * RNN_T;
  f32x4 xc = *(const f32x4*)px;

  // anti-phase stagger: co-resident pair is likely (b, b+256); delay the
  // second-round blocks ~half a step so their epi overlaps our MFMA phase.
  if (blockIdx.x >= 256) {
    float acc = (float)lane;
    #pragma unroll 1
    for (int i = 0; i < 160; ++i) acc = __builtin_fmaf(acc, 0.9999f, 1.0f);
    if (acc == 12345.678f) rs[0] = acc;   // unreachable; keeps loop alive
  }

  const i32x4 ZI = {0,0,0,0};
  u32x2 ownA = {0u,0u}, ownB = {0u,0u};   // own half frags (h(0) = 0)

  __syncthreads();

  for (int t4 = 0; t4 < RNN_T/4; ++t4) {
    f32x4 xn = xc;
    if (t4 + 1 < RNN_T/4) xn = *(const f32x4*)(px + 4*t4 + 4);
    #pragma unroll
    for (int qq = 0; qq < 4; ++qq) {
      const int rb = qq & 1, wb2 = rb ^ 1;
      const float xv = xc[qq];

      // 6 x ds_read_b64 (conflict-free stride-8)
      const u32x2 poA = hbuf[rb][sw][0][hw^1][lane];   // own slot, partner half
      const u32x2 poB = hbuf[rb][sw][1][hw^1][lane];
      const u32x2 oa0 = hbuf[rb][so][0][0][lane];      // other slot, both halves
      const u32x2 oa1 = hbuf[rb][so][0][1][lane];
      const u32x2 ob0 = hbuf[rb][so][1][0][lane];
      const u32x2 ob1 = hbuf[rb][so][1][1][lane];
      MEMPIN();

      // own-slot frags: own half at regs [2hw, 2hw+1]
      i32x4 FaOwn, FbOwn;
      {
        const unsigned s0 = hw ? poA[0] : ownA[0];
        const unsigned s1 = hw ? poA[1] : ownA[1];
        const unsigned s2 = hw ? ownA[0] : poA[0];
        const unsigned s3 = hw ? ownA[1] : poA[1];
        FaOwn = i32x4{(int)s0,(int)s1,(int)s2,(int)s3};
        const unsigned t0 = hw ? poB[0] : ownB[0];
        const unsigned t1 = hw ? poB[1] : ownB[1];
        const unsigned t2 = hw ? ownB[0] : poB[0];
        const unsigned t3 = hw ? ownB[1] : poB[1];
        FbOwn = i32x4{(int)t0,(int)t1,(int)t2,(int)t3};
      }
      const i32x4 FaOth = i32x4{(int)oa0[0],(int)oa0[1],(int)oa1[0],(int)oa1[1]};
      const i32x4 FbOth = i32x4{(int)ob0[0],(int)ob0[1],(int)ob1[0],(int)ob1[1]};

      // 12 i8 MFMAs: 3 chains x 2 mt x 2 slots (own slot first: partner-half
      // read is the only LDS dependency of the first 6)
      i32x4 P1[2], P2[2], P3[2];
      __builtin_amdgcn_s_setprio(1);
      #pragma unroll
      for (int mt = 0; mt < 2; ++mt) {
        P1[mt] = mfma_i8(WA[mt][0], FaOwn, ZI);
        P2[mt] = mfma_i8(WA[mt][0], FbOwn, ZI);
        P3[mt] = mfma_i8(WB[mt][0], FaOwn, ZI);
      }
      #pragma unroll
      for (int mt = 0; mt < 2; ++mt) {
        P1[mt] = mfma_i8(WA[mt][1], FaOth, P1[mt]);
        P2[mt] = mfma_i8(WA[mt][1], FbOth, P2[mt]);
        P3[mt] = mfma_i8(WB[mt][1], FaOth, P3[mt]);
      }
      __builtin_amdgcn_s_setprio(0);

      // epilogue: pre-act -> tanh -> 15-bit quant -> (a,b) int8 pack
      unsigned apk[2], bpk[2];
      #pragma unroll
      for (int mt = 0; mt < 2; ++mt) {
        unsigned pa = 0, pb = 0;
        #pragma unroll
        for (int r = 0; r < 4; ++r) {
          const int   X  = ((P1[mt][r] << 8) + P2[mt][r]) + P3[mt][r];
          const float v  = __builtin_fmaf(kk[mt][r], (float)X,
                            __builtin_fmaf(wx[mt][r], xv, bh[mt][r]));
          const float e  = __builtin_amdgcn_exp2f(v * 2.885390081777927f);
          const float rc = __builtin_amdgcn_rcpf(e + 1.0f);
          // qoff = QS*tanh(v) + 32768.5 > 0; trunc = round-half-up of QS*t
          const float qo = __builtin_fmaf(rc, -65024.0f, 65280.5f);
          const int q128 = (int)qo - 32640;          // rint(t*QS) + 128
          pa |= ((unsigned)((q128 >> 8) & 255)) << (8*r);       // a byte
          pb |= ((unsigned)((q128 ^ 128) & 255)) << (8*r);      // b = (q&255)-128
        }
        apk[mt] = pa; bpk[mt] = pb;
      }
      ownA = u32x2{apk[0], apk[1]};
      ownB = u32x2{bpk[0], bpk[1]};

      // publish own half (2 x ds_write_b64)
      hbuf[wb2][sw][0][hw][lane] = ownA;
      hbuf[wb2][sw][1][hw][lane] = ownB;
      BAR();
    }
    xc = xn;
  }

  __syncthreads();

  // ---- projection: out[b][c] = w_ph[c,:] . h_last[:,b] + b_p[c] ----
  // t=2047 wrote buffer 0; h = (256*a + b) / QS.
  {
    const int c = tid >> 4;
    const int n = tid & 15;
    if (c < RNN_C) {
      float sum = b_p[c];
      for (int k = 0; k < RNN_H; ++k) {
        const int s  = k >> 6;
        const int ko = k & 63;
        const int g2 = (ko >> 2) & 3;
        const int j  = (ko & 3) + 4*((ko >> 4) & 1) + 8*(ko >> 5);
        const int half = j >> 3, jj = j & 7;
        const signed char* pa = (const signed char*)&hbuf[0][s][0][half][16*g2 + n];
        const signed char* pb = (const signed char*)&hbuf[0][s][1][half][16*g2 + n];
        const int qv = 256*(int)pa[jj] + (int)pb[jj];
        sum = __builtin_fmaf(w_ph[c*RNN_H + k], qv * (1.0f/QSF), sum);
      }
      out[(size_t)(n0 + n)*RNN_C + c] = sum;
    }
  }
}

extern "C" void kernel_launch(void* const* d_in, const int* in_sizes, int n_in,
                              void* d_out, int out_size, void* d_ws, size_t ws_size,
                              hipStream_t stream) {
  (void)in_sizes; (void)n_in; (void)out_size; (void)d_ws; (void)ws_size;
  const float* x    = (const float*)d_in[0];
  const float* w_hx = (const float*)d_in[1];
  const float* w_hh = (const float*)d_in[2];
  const float* b_h  = (const float*)d_in[3];
  const float* w_ph = (const float*)d_in[4];
  const float* b_p  = (const float*)d_in[5];
  float* out = (float*)d_out;
  rnn_fused<<<dim3(RNN_B/BLK_N), dim3(256), 0, stream>>>(x, w_hx, w_hh, b_h, w_ph, b_p, out);
}

// Round 11
// 1004.967 us; speedup vs baseline: 2.4068x; 1.4000x over previous
//
#include <hip/hip_runtime.h>

typedef int      i32x4 __attribute__((ext_vector_type(4)));
typedef float    f32x4 __attribute__((ext_vector_type(4)));
typedef unsigned u32x2 __attribute__((ext_vector_type(2)));

#define RNN_H 128
#define RNN_T 2048
#define RNN_B 8192
#define RNN_C 10
#define BLK_N 16
#define QSW 32512.0f            // 127*256: fixed-point scale for W and h
#define K2E 2.885390081777927f  // 2*log2(e), folded into kk/wx/bh

// LDS-only barrier: drain ds ops, never vmcnt (x prefetch stays in flight).
#define BAR() asm volatile("s_waitcnt lgkmcnt(0)\n\ts_barrier" ::: "memory")
#define MEMPIN() asm volatile("" ::: "memory")

__device__ __forceinline__ i32x4 mfma_i8(i32x4 a, i32x4 b, i32x4 c) {
  return __builtin_amdgcn_mfma_i32_16x16x64_i8(a, b, c, 0, 0, 0);
}

// k-bijection for 16x16x64 i8 frags (byte p of the 4-dword operand, lane
// group g = lane>>4): k = 64*slot + 4g + (p&3) + 16*jg(p>>2). Each wave uses
// its OWN jg permutation for its own slot -- own-half j-groups (2hw, 2hw+1)
// sit at frag dwords 0,1 and the partner half at dwords 2,3 -- with the
// A-fill permuted identically, so the sum over k is unchanged and fragment
// assembly needs NO runtime muxes. LDS stores remain in natural order.
// h = q/32512, q = 256a + b (a,b int8; a = (q+128)>>8, b = q - 256a = low
// byte of q). W row-scaled: Wq = rint(w*32512/mx), wa = (Wq+128)>>8,
// wb = Wq - 256wa. X = 256*P1 + P23 with P1 = S wa*a, P23 = S(wa*b + wb*a)
// (wb*b dropped, ~2e-5 rel). v = (mx/(127*32512))*X + wx*x + bh.

__global__ __launch_bounds__(256, 2)
void rnn_fused(const float* __restrict__ x, const float* __restrict__ w_hx,
               const float* __restrict__ w_hh, const float* __restrict__ b_h,
               const float* __restrict__ w_ph, const float* __restrict__ b_p,
               float* __restrict__ out)
{
  // h double-buffered: [buf][slot(2)][part a/b][half(2)][lane(64)] x 8B = 8 KiB
  __shared__ u32x2 hbuf[2][2][2][2][64];
  __shared__ float rs[128];   // per-row W scales for C/D-lane redistribution

  const int tid  = threadIdx.x;
  const int lane = tid & 63;
  const int wv   = tid >> 6;       // 0..3: rows [32wv, 32wv+32)
  const int g    = lane >> 4;
  const int l15  = lane & 15;
  const int n0   = blockIdx.x * BLK_N;
  const int sw = wv >> 1, hw = wv & 1, so = sw ^ 1;

  { // zero h(0) = buffer 0 (512 u32x2 entries)
    u32x2 z = {0u, 0u};
    u32x2* p = &hbuf[0][0][0][0][0];
    p[tid] = z; p[tid + 256] = z;
  }

  // ---- W quantization: per-row 15-bit fixed point, split to int8 (wa, wb).
  // li = 0: own slot with per-wave jg permutation; li = 1: other slot natural.
  i32x4 WA[2][2], WB[2][2];
  float rm[2];
  #pragma unroll
  for (int mt = 0; mt < 2; ++mt) {
    const float* wrow = w_hh + (size_t)(wv*32 + mt*16 + l15)*RNN_H + 4*g;
    float vals[2][4][4];
    float mx = 0.0f;
    #pragma unroll
    for (int li = 0; li < 2; ++li) {
      const int s = li ? so : sw;
      #pragma unroll
      for (int d = 0; d < 4; ++d) {
        const int jg = li ? d : ((d < 2) ? (2*hw + d) : (2*(hw^1) + (d-2)));
        f32x4 v = *(const f32x4*)(wrow + s*64 + jg*16);
        #pragma unroll
        for (int r = 0; r < 4; ++r) { vals[li][d][r] = v[r]; mx = fmaxf(mx, fabsf(v[r])); }
      }
    }
    mx = fmaxf(mx, __shfl_xor(mx, 16));   // combine the 4 g-lanes of this row
    mx = fmaxf(mx, __shfl_xor(mx, 32));
    const float inv = (mx > 0.0f) ? (QSW / mx) : 0.0f;
    rm[mt] = mx * (1.0f / QSW);
    #pragma unroll
    for (int li = 0; li < 2; ++li)
      #pragma unroll
      for (int d = 0; d < 4; ++d) {
        unsigned pa = 0, pb = 0;
        #pragma unroll
        for (int r = 0; r < 4; ++r) {
          const int Wq  = (int)rintf(vals[li][d][r] * inv);  // |Wq| <= 32512
          const int wa  = (Wq + 128) >> 8;                   // [-127, 127]
          const int wbv = Wq - (wa << 8);                    // [-128, 127]
          pa |= ((unsigned)(wa  & 255)) << (8*r);
          pb |= ((unsigned)(wbv & 255)) << (8*r);
        }
        WA[mt][li][d] = (int)pa;
        WB[mt][li][d] = (int)pb;
      }
  }

  if (g == 0) {                       // publish row scales (rows 32wv+16mt+l15)
    rs[wv*32 +  0 + l15] = rm[0];
    rs[wv*32 + 16 + l15] = rm[1];
  }
  __syncthreads();

  // per-C/D-reg constants (K2E folded): m = 32wv + 16mt + 4g + r
  f32x4 kk2[2], wx2[2], bh2[2];
  #pragma unroll
  for (int mt = 0; mt < 2; ++mt)
    #pragma unroll
    for (int r = 0; r < 4; ++r) {
      const int m = wv*32 + mt*16 + 4*g + r;
      kk2[mt][r] = rs[m] * (K2E / 127.0f);
      wx2[mt][r] = w_hx[m] * K2E;
      bh2[mt][r] = b_h[m] * K2E;
    }

  const float* px = x + (size_t)(n0 + l15) * RNN_T;
  f32x4 xc = *(const f32x4*)px;

  const i32x4 ZI = {0,0,0,0};
  u32x2 ownA = {0u,0u}, ownB = {0u,0u};   // own half frags (h(0) = 0)

  // epilogue constants (VGPR-resident; v_perm/v_pk_add take no literals)
  const unsigned c0080 = 0x00800080u;   // +128 per i16 (a-byte rounding)
  const unsigned selA  = 0x07050301u;   // a-bytes: bytes 1,3 of each i16 pair
  const unsigned selB  = 0x06040200u;   // b-bytes: bytes 0,2
  const float TPP = 32512.0f / 32767.0f;  // pknorm prescale -> q = rint(t*32512)
  const float TPN = -2.0f * TPP;

  __syncthreads();

  for (int t4 = 0; t4 < RNN_T/4; ++t4) {
    f32x4 xn = xc;
    if (t4 + 1 < RNN_T/4) xn = *(const f32x4*)(px + 4*t4 + 4);
    #pragma unroll
    for (int qq = 0; qq < 4; ++qq) {
      const int rb = qq & 1, wb2 = rb ^ 1;
      const float xv = xc[qq];

      // 6 x ds_read_b64 (conflict-free): partner half first (feeds MFMAs 1-6)
      const u32x2 poA = hbuf[rb][sw][0][hw^1][lane];
      const u32x2 poB = hbuf[rb][sw][1][hw^1][lane];
      const u32x2 oa0 = hbuf[rb][so][0][0][lane];
      const u32x2 oa1 = hbuf[rb][so][0][1][lane];
      const u32x2 ob0 = hbuf[rb][so][1][0][lane];
      const u32x2 ob1 = hbuf[rb][so][1][1][lane];
      MEMPIN();

      // static fragment assembly (no muxes; own half always dwords 0,1)
      const i32x4 FaOwn = {(int)ownA[0], (int)ownA[1], (int)poA[0], (int)poA[1]};
      const i32x4 FbOwn = {(int)ownB[0], (int)ownB[1], (int)poB[0], (int)poB[1]};
      const i32x4 FaOth = {(int)oa0[0], (int)oa0[1], (int)oa1[0], (int)oa1[1]};
      const i32x4 FbOth = {(int)ob0[0], (int)ob0[1], (int)ob1[0], (int)ob1[1]};

      // 12 i8 MFMAs, 4 chains (P1 x2 depth 2, P23 x2 depth 4)
      i32x4 P1[2], P23[2];
      __builtin_amdgcn_s_setprio(1);
      P1[0]  = mfma_i8(WA[0][0], FaOwn, ZI);
      P1[1]  = mfma_i8(WA[1][0], FaOwn, ZI);
      P23[0] = mfma_i8(WB[0][0], FaOwn, ZI);
      P23[1] = mfma_i8(WB[1][0], FaOwn, ZI);
      P23[0] = mfma_i8(WA[0][0], FbOwn, P23[0]);
      P23[1] = mfma_i8(WA[1][0], FbOwn, P23[1]);
      P1[0]  = mfma_i8(WA[0][1], FaOth, P1[0]);
      P1[1]  = mfma_i8(WA[1][1], FaOth, P1[1]);
      P23[0] = mfma_i8(WB[0][1], FaOth, P23[0]);
      P23[1] = mfma_i8(WB[1][1], FaOth, P23[1]);
      P23[0] = mfma_i8(WA[0][1], FbOth, P23[0]);
      P23[1] = mfma_i8(WA[1][1], FbOth, P23[1]);
      __builtin_amdgcn_s_setprio(0);

      // epilogue: X -> tanh (exp2+rcp) -> pknorm i16 -> byte split via perm
      unsigned napk[2], nbpk[2];
      #pragma unroll
      for (int mt = 0; mt < 2; ++mt) {
        float tp0, tp1, tp2, tp3;
        {
          const int X0 = (P1[mt][0] << 8) + P23[mt][0];
          const int X1 = (P1[mt][1] << 8) + P23[mt][1];
          const int X2 = (P1[mt][2] << 8) + P23[mt][2];
          const int X3 = (P1[mt][3] << 8) + P23[mt][3];
          const float v0 = __builtin_fmaf(kk2[mt][0], (float)X0,
                             __builtin_fmaf(wx2[mt][0], xv, bh2[mt][0]));
          const float v1 = __builtin_fmaf(kk2[mt][1], (float)X1,
                             __builtin_fmaf(wx2[mt][1], xv, bh2[mt][1]));
          const float v2 = __builtin_fmaf(kk2[mt][2], (float)X2,
                             __builtin_fmaf(wx2[mt][2], xv, bh2[mt][2]));
          const float v3 = __builtin_fmaf(kk2[mt][3], (float)X3,
                             __builtin_fmaf(wx2[mt][3], xv, bh2[mt][3]));
          const float e0 = __builtin_amdgcn_exp2f(v0);
          const float e1 = __builtin_amdgcn_exp2f(v1);
          const float e2 = __builtin_amdgcn_exp2f(v2);
          const float e3 = __builtin_amdgcn_exp2f(v3);
          const float r0 = __builtin_amdgcn_rcpf(e0 + 1.0f);
          const float r1 = __builtin_amdgcn_rcpf(e1 + 1.0f);
          const float r2 = __builtin_amdgcn_rcpf(e2 + 1.0f);
          const float r3 = __builtin_amdgcn_rcpf(e3 + 1.0f);
          tp0 = __builtin_fmaf(r0, TPN, TPP);
          tp1 = __builtin_fmaf(r1, TPN, TPP);
          tp2 = __builtin_fmaf(r2, TPN, TPP);
          tp3 = __builtin_fmaf(r3, TPN, TPP);
        }
        unsigned q01, q23, a01, a23, pa, pb;
        asm("v_cvt_pknorm_i16_f32 %0, %1, %2" : "=v"(q01) : "v"(tp0), "v"(tp1));
        asm("v_cvt_pknorm_i16_f32 %0, %1, %2" : "=v"(q23) : "v"(tp2), "v"(tp3));
        asm("v_pk_add_i16 %0, %1, %2" : "=v"(a01) : "v"(q01), "v"(c0080));
        asm("v_pk_add_i16 %0, %1, %2" : "=v"(a23) : "v"(q23), "v"(c0080));
        asm("v_perm_b32 %0, %1, %2, %3" : "=v"(pa) : "v"(a23), "v"(a01), "v"(selA));
        asm("v_perm_b32 %0, %1, %2, %3" : "=v"(pb) : "v"(q23), "v"(q01), "v"(selB));
        napk[mt] = pa; nbpk[mt] = pb;
      }
      ownA = u32x2{napk[0], napk[1]};
      ownB = u32x2{nbpk[0], nbpk[1]};

      // publish own half (2 x ds_write_b64, natural physical layout)
      hbuf[wb2][sw][0][hw][lane] = ownA;
      hbuf[wb2][sw][1][hw][lane] = ownB;
      BAR();
    }
    xc = xn;
  }

  __syncthreads();

  // ---- projection: out[b][c] = w_ph[c,:] . h_last[:,b] + b_p[c] ----
  // t=2047 wrote buffer 0; h = (256*a + b) / 32512.
  {
    const int c = tid >> 4;
    const int n = tid & 15;
    if (c < RNN_C) {
      float sum = b_p[c];
      for (int k = 0; k < RNN_H; ++k) {
        const int s  = k >> 6;
        const int ko = k & 63;
        const int g2 = (ko >> 2) & 3;
        const int j  = (ko & 3) + 4*(ko >> 4);
        const int half = j >> 3, jj = j & 7;
        const signed char* pa = (const signed char*)&hbuf[0][s][0][half][16*g2 + n];
        const signed char* pb = (const signed char*)&hbuf[0][s][1][half][16*g2 + n];
        const int qv = 256*(int)pa[jj] + (int)pb[jj];
        sum = __builtin_fmaf(w_ph[c*RNN_H + k], qv * (1.0f/QSW), sum);
      }
      out[(size_t)(n0 + n)*RNN_C + c] = sum;
    }
  }
}

extern "C" void kernel_launch(void* const* d_in, const int* in_sizes, int n_in,
                              void* d_out, int out_size, void* d_ws, size_t ws_size,
                              hipStream_t stream) {
  (void)in_sizes; (void)n_in; (void)out_size; (void)d_ws; (void)ws_size;
  const float* x    = (const float*)d_in[0];
  const float* w_hx = (const float*)d_in[1];
  const float* w_hh = (const float*)d_in[2];
  const float* b_h  = (const float*)d_in[3];
  const float* w_ph = (const float*)d_in[4];
  const float* b_p  = (const float*)d_in[5];
  float* out = (float*)d_out;
  rnn_fused<<<dim3(RNN_B/BLK_N), dim3(256), 0, stream>>>(x, w_hx, w_hh, b_h, w_ph, b_p, out);
}